// Round 1
// baseline (474.351 us; speedup 1.0000x reference)
//
#include <hip/hip_runtime.h>

#define N_UTT 4000
#define NDIM 256
#define B_DIA 100
#define L_DIA 40
#define NNODE 12000   // 3*N_UTT
#define NLAYERS 4

// ---------------------------------------------------------------------------
// K1: build x = concat(a, v, l + spk_emb[argmax(q)]) and per-row inverse norms
// one block (256 thr) per node row
__global__ void k_build_x(const float* __restrict__ a, const float* __restrict__ v,
                          const float* __restrict__ l, const float* __restrict__ qmask,
                          const float* __restrict__ spk, float* __restrict__ x,
                          float* __restrict__ invn) {
  int r = blockIdx.x;          // 0..11999
  int t = threadIdx.x;         // 0..255
  int m = r / N_UTT;
  int i = r - m * N_UTT;
  float val;
  if (m == 0) val = a[i * NDIM + t];
  else if (m == 1) val = v[i * NDIM + t];
  else {
    int b = i / L_DIA, p = i - b * L_DIA;
    // qmask shape (L, B, 2): flat (p*B + b)*2 + s
    float q0 = qmask[p * (B_DIA * 2) + b * 2 + 0];
    float q1 = qmask[p * (B_DIA * 2) + b * 2 + 1];
    int s = (q1 > q0) ? 1 : 0;   // argmax, first-wins on tie
    val = l[i * NDIM + t] + spk[s * NDIM + t];
  }
  x[r * NDIM + t] = val;
  float ss = val * val;
  #pragma unroll
  for (int off = 32; off > 0; off >>= 1) ss += __shfl_down(ss, off);
  __shared__ float wsum[4];
  int wid = t >> 6, lane = t & 63;
  if (lane == 0) wsum[wid] = ss;
  __syncthreads();
  if (t == 0) invn[r] = rsqrtf(wsum[0] + wsum[1] + wsum[2] + wsum[3]);
}

// ---------------------------------------------------------------------------
// K2: per-(modality, dialogue) 40x40 angular-similarity block
__global__ void k_sim(const float* __restrict__ x, const float* __restrict__ invn,
                      float* __restrict__ sim) {
  int mb = blockIdx.x;          // m*100 + b
  int m = mb / B_DIA, b = mb - m * B_DIA;
  int t = threadIdx.x;
  __shared__ float xt[L_DIA][NDIM];
  __shared__ float vin[L_DIA];
  int base = m * N_UTT + b * L_DIA;
  for (int e = t; e < L_DIA * NDIM; e += 256) {
    int r = e >> 8, c = e & 255;
    xt[r][c] = x[(base + r) * NDIM + c];
  }
  if (t < L_DIA) vin[t] = invn[base + t];
  __syncthreads();
  const float inv_pi = 0.31830988618379067f;
  for (int p = t; p < L_DIA * L_DIA; p += 256) {
    int ii = p / L_DIA, jj = p - ii * L_DIA;
    float dot = 0.f;
    #pragma unroll 8
    for (int k = 0; k < NDIM; k++) dot = fmaf(xt[ii][k], xt[jj][k], dot);
    float cs = dot * vin[ii] * vin[jj] * 0.99999f;
    cs = fminf(fmaxf(cs, -1.f), 1.f);
    sim[mb * (L_DIA * L_DIA) + p] = 1.0f - acosf(cs) * inv_pi;
  }
}

// ---------------------------------------------------------------------------
// K3: cross-modal diagonal similarities: pairs (a,v)=0, (a,l)=1, (v,l)=2
__global__ void k_cross(const float* __restrict__ x, const float* __restrict__ invn,
                        float* __restrict__ cross) {
  int i = blockIdx.x;           // utterance 0..3999
  int t = threadIdx.x;
  float xa = x[(0 * N_UTT + i) * NDIM + t];
  float xv = x[(1 * N_UTT + i) * NDIM + t];
  float xl = x[(2 * N_UTT + i) * NDIM + t];
  float s0 = xa * xv, s1 = xa * xl, s2 = xv * xl;
  #pragma unroll
  for (int off = 32; off > 0; off >>= 1) {
    s0 += __shfl_down(s0, off);
    s1 += __shfl_down(s1, off);
    s2 += __shfl_down(s2, off);
  }
  __shared__ float w0[4], w1[4], w2[4];
  int wid = t >> 6, lane = t & 63;
  if (lane == 0) { w0[wid] = s0; w1[wid] = s1; w2[wid] = s2; }
  __syncthreads();
  if (t == 0) {
    float ina = invn[i], inv = invn[N_UTT + i], inl = invn[2 * N_UTT + i];
    const float inv_pi = 0.31830988618379067f;
    float d0 = fminf(fmaxf((w0[0]+w0[1]+w0[2]+w0[3]) * ina * inv * 0.99999f, -1.f), 1.f);
    float d1 = fminf(fmaxf((w1[0]+w1[1]+w1[2]+w1[3]) * ina * inl * 0.99999f, -1.f), 1.f);
    float d2 = fminf(fmaxf((w2[0]+w2[1]+w2[2]+w2[3]) * inv * inl * 0.99999f, -1.f), 1.f);
    cross[0 * N_UTT + i] = 1.f - acosf(d0) * inv_pi;
    cross[1 * N_UTT + i] = 1.f - acosf(d1) * inv_pi;
    cross[2 * N_UTT + i] = 1.f - acosf(d2) * inv_pi;
  }
}

// ---------------------------------------------------------------------------
// K4: degrees -> dinv = d^(-1/2)
__global__ void k_degree(const float* __restrict__ sim, const float* __restrict__ cross,
                         float* __restrict__ dinv) {
  int r = blockIdx.x * blockDim.x + threadIdx.x;
  if (r >= NNODE) return;
  int m = r / N_UTT, i = r - m * N_UTT;
  int b = i / L_DIA, p = i - b * L_DIA;
  const float* srow = sim + ((m * B_DIA + b) * L_DIA + p) * L_DIA;
  float d = 0.f;
  #pragma unroll 10
  for (int q = 0; q < L_DIA; q++) d += srow[q];
  if (m == 0)      d += cross[i]          + cross[N_UTT + i];
  else if (m == 1) d += cross[i]          + cross[2 * N_UTT + i];
  else             d += cross[N_UTT + i]  + cross[2 * N_UTT + i];
  dinv[r] = rsqrtf(d);
}

// ---------------------------------------------------------------------------
// K5: fold dinv into sim and cross (symmetric normalization)
__global__ void k_norm(float* __restrict__ sim, float* __restrict__ cross,
                       const float* __restrict__ dinv) {
  int e = blockIdx.x * blockDim.x + threadIdx.x;
  const int NSIM = 3 * B_DIA * L_DIA * L_DIA;   // 480000
  if (e < NSIM) {
    int mb = e / (L_DIA * L_DIA), pq = e - mb * (L_DIA * L_DIA);
    int m = mb / B_DIA, b = mb - m * B_DIA;
    int p = pq / L_DIA, q = pq - p * L_DIA;
    int np_ = m * N_UTT + b * L_DIA + p;
    int nq  = m * N_UTT + b * L_DIA + q;
    sim[e] *= dinv[np_] * dinv[nq];
  } else {
    int e2 = e - NSIM;
    if (e2 < 3 * N_UTT) {
      int pair = e2 / N_UTT, i = e2 - pair * N_UTT;
      int m = (pair == 2) ? 1 : 0;
      int n = (pair == 0) ? 1 : 2;
      cross[e2] *= dinv[m * N_UTT + i] * dinv[n * N_UTT + i];
    }
  }
}

// ---------------------------------------------------------------------------
// GEMM: C(12000x256) = f(A(12000x256) @ W(256x256))
// MODE 0: relu(A@W + bias)           (h0)
// MODE 1: relu(theta*(A@W) + (1-theta)*A)   (layer update; A = support)
template<int MODE>
__global__ void k_gemm(const float* __restrict__ A, const float* __restrict__ W,
                       const float* __restrict__ bias, float* __restrict__ C,
                       float theta) {
  __shared__ float As[16][65];
  __shared__ float Bs[16][65];
  int bm = blockIdx.y * 64;
  int bn = blockIdx.x * 64;
  int tid = threadIdx.x;
  int tx = tid & 15, ty = tid >> 4;
  float acc[4][4] = {{0.f}};
  for (int k0 = 0; k0 < NDIM; k0 += 16) {
    #pragma unroll
    for (int i = 0; i < 4; i++) {
      int e = tid + 256 * i;
      int mm = e >> 4, kk = e & 15;
      int row = bm + mm; if (row >= NNODE) row = NNODE - 1;
      As[kk][mm] = A[row * NDIM + k0 + kk];
      int kb = e >> 6, nn = e & 63;
      Bs[kb][nn] = W[(k0 + kb) * NDIM + bn + nn];
    }
    __syncthreads();
    #pragma unroll
    for (int k = 0; k < 16; k++) {
      float ra[4], rb[4];
      #pragma unroll
      for (int i = 0; i < 4; i++) ra[i] = As[k][ty * 4 + i];
      #pragma unroll
      for (int j = 0; j < 4; j++) rb[j] = Bs[k][tx * 4 + j];
      #pragma unroll
      for (int i = 0; i < 4; i++)
        #pragma unroll
        for (int j = 0; j < 4; j++)
          acc[i][j] = fmaf(ra[i], rb[j], acc[i][j]);
    }
    __syncthreads();
  }
  #pragma unroll
  for (int i = 0; i < 4; i++) {
    int row = bm + ty * 4 + i;
    if (row >= NNODE) continue;
    #pragma unroll
    for (int j = 0; j < 4; j++) {
      int col = bn + tx * 4 + j;
      float vv;
      if (MODE == 0) {
        vv = acc[i][j] + bias[col];
      } else {
        float sup = A[row * NDIM + col];
        vv = theta * acc[i][j] + (1.f - theta) * sup;
      }
      C[row * NDIM + col] = fmaxf(vv, 0.f);
    }
  }
}

// ---------------------------------------------------------------------------
// adj apply + support: sup = 0.9*(adjnorm @ h) + 0.1*h0, structured
__global__ void k_adj(const float* __restrict__ h, const float* __restrict__ h0,
                      const float* __restrict__ sim, const float* __restrict__ cross,
                      float* __restrict__ sup) {
  int mb = blockIdx.x;          // m*100 + b
  int m = mb / B_DIA, b = mb - m * B_DIA;
  int t = threadIdx.x;
  __shared__ float Sb[L_DIA][L_DIA];
  __shared__ float hb[L_DIA][NDIM];
  const float* simblk = sim + mb * (L_DIA * L_DIA);
  for (int e = t; e < L_DIA * L_DIA; e += 256)
    Sb[e / L_DIA][e % L_DIA] = simblk[e];
  int base = m * N_UTT + b * L_DIA;
  for (int e = t; e < L_DIA * NDIM; e += 256) {
    int r = e >> 8, c = e & 255;
    hb[r][c] = h[(base + r) * NDIM + c];
  }
  __syncthreads();
  for (int p = 0; p < L_DIA; p++) {
    float acc = 0.f;
    #pragma unroll 10
    for (int q = 0; q < L_DIA; q++) acc = fmaf(Sb[p][q], hb[q][t], acc);
    int i = b * L_DIA + p;
    float c0, c1; int o0, o1;
    if (m == 0)      { c0 = cross[i];           o0 = N_UTT + i;     c1 = cross[N_UTT + i];     o1 = 2 * N_UTT + i; }
    else if (m == 1) { c0 = cross[i];           o0 = i;             c1 = cross[2 * N_UTT + i]; o1 = 2 * N_UTT + i; }
    else             { c0 = cross[N_UTT + i];   o0 = i;             c1 = cross[2 * N_UTT + i]; o1 = N_UTT + i; }
    acc += c0 * h[o0 * NDIM + t] + c1 * h[o1 * NDIM + t];
    int node = base + p;
    sup[node * NDIM + t] = 0.9f * acc + 0.1f * h0[node * NDIM + t];
  }
}

// ---------------------------------------------------------------------------
// output assembly: out[i] = [a_i, h_a_i, v_i, h_v_i, l_i, h_l_i]
__global__ void k_out(const float* __restrict__ x, const float* __restrict__ h,
                      float* __restrict__ out) {
  int i = blockIdx.x;
  int t = threadIdx.x;
  #pragma unroll
  for (int m = 0; m < 3; m++) {
    out[i * 1536 + m * 512 + t]       = x[(m * N_UTT + i) * NDIM + t];
    out[i * 1536 + m * 512 + 256 + t] = h[(m * N_UTT + i) * NDIM + t];
  }
}

// ---------------------------------------------------------------------------
extern "C" void kernel_launch(void* const* d_in, const int* in_sizes, int n_in,
                              void* d_out, int out_size, void* d_ws, size_t ws_size,
                              hipStream_t stream) {
  const float* a     = (const float*)d_in[0];
  const float* v     = (const float*)d_in[1];
  const float* l     = (const float*)d_in[2];
  const float* qmask = (const float*)d_in[3];
  const float* spk   = (const float*)d_in[4];
  const float* W0    = (const float*)d_in[5];
  const float* b0    = (const float*)d_in[6];
  const float* Wc    = (const float*)d_in[7];
  float* out = (float*)d_out;
  float* ws  = (float*)d_ws;

  float* x     = ws;                    // 3,072,000
  float* h0    = ws + 3072000;          // 3,072,000
  float* hA    = ws + 6144000;          // 3,072,000
  float* hB    = ws + 9216000;          // 3,072,000
  float* tmp   = ws + 12288000;         // 3,072,000 (support)
  float* sim   = ws + 15360000;         // 480,000
  float* cross = ws + 15840000;         // 12,000
  float* invn  = ws + 15852000;         // 12,000
  float* dinv  = ws + 15864000;         // 12,000
  // total: 15,876,000 floats = 63.5 MB

  k_build_x<<<NNODE, 256, 0, stream>>>(a, v, l, qmask, spk, x, invn);
  k_sim<<<3 * B_DIA, 256, 0, stream>>>(x, invn, sim);
  k_cross<<<N_UTT, 256, 0, stream>>>(x, invn, cross);
  k_degree<<<(NNODE + 255) / 256, 256, 0, stream>>>(sim, cross, dinv);
  k_norm<<<(3 * B_DIA * L_DIA * L_DIA + 3 * N_UTT + 255) / 256, 256, 0, stream>>>(sim, cross, dinv);

  k_gemm<0><<<dim3(NDIM / 64, (NNODE + 63) / 64), 256, 0, stream>>>(x, W0, b0, h0, 0.f);

  const float thetas[NLAYERS] = {0.40546510810816438f, 0.22314355131420976f,
                                 0.15415067982725836f, 0.11778303565638346f};
  const float* hcur = h0;
  float* houts[NLAYERS] = {hA, hB, hA, hB};
  for (int i = 0; i < NLAYERS; i++) {
    k_adj<<<3 * B_DIA, 256, 0, stream>>>(hcur, h0, sim, cross, tmp);
    k_gemm<1><<<dim3(NDIM / 64, (NNODE + 63) / 64), 256, 0, stream>>>(
        tmp, Wc + i * NDIM * NDIM, nullptr, houts[i], thetas[i]);
    hcur = houts[i];
  }
  k_out<<<N_UTT, 256, 0, stream>>>(x, hcur, out);
}